// Round 2
// baseline (944.995 us; speedup 1.0000x reference)
//
#include <hip/hip_runtime.h>

#define NF 29
#define INF 32
#define HD 64
#define NL 7

// constant-address-space cast => forces scalar (SMEM) loads for uniform addrs
#define AS4 __attribute__((address_space(4)))
typedef const AS4 float* cfp;
__device__ __forceinline__ cfp to_const(const float* p) {
    return (cfp)(unsigned long long)p;
}

// ---------------- h0 = concat(x, pos) ----------------
__global__ void build_h0_kernel(const float* __restrict__ x, const float* __restrict__ pos,
                                float* __restrict__ h0, int N) {
    int t = blockIdx.x * blockDim.x + threadIdx.x;
    if (t >= N * INF) return;
    int n = t >> 5, f = t & 31;
    h0[t] = (f < NF) ? x[n * NF + f] : pos[n * 3 + (f - NF)];
}

// ---------------- CSR build ----------------
__global__ void hist_kernel(const int* __restrict__ dst, int E, int* __restrict__ deg) {
    int t = blockIdx.x * blockDim.x + threadIdx.x;
    if (t < E) atomicAdd(&deg[dst[t]], 1);
}

// 3-phase scan: block sums -> scan partials -> rescan with offset
__global__ void scan1_kernel(const int* __restrict__ deg, int* __restrict__ part, int N) {
    int t = threadIdx.x;
    int i = blockIdx.x * 256 + t;
    int v = (i < N) ? deg[i] : 0;
    for (int off = 32; off > 0; off >>= 1) v += __shfl_down(v, off);
    __shared__ int ws[4];
    if ((t & 63) == 0) ws[t >> 6] = v;
    __syncthreads();
    if (t == 0) part[blockIdx.x] = ws[0] + ws[1] + ws[2] + ws[3];
}

__global__ void scan2_kernel(const int* __restrict__ part, int* __restrict__ partx, int nPart) {
    __shared__ int s[256];
    int t = threadIdx.x;
    s[t] = (t < nPart) ? part[t] : 0;
    __syncthreads();
    for (int off = 1; off < 256; off <<= 1) {
        int v = (t >= off) ? s[t - off] : 0;
        __syncthreads();
        s[t] += v;
        __syncthreads();
    }
    partx[t] = (t == 0) ? 0 : s[t - 1];
}

__global__ void scan3_kernel(const int* __restrict__ deg, const int* __restrict__ partx,
                             int* __restrict__ rowptr, int N) {
    int t = threadIdx.x;
    int lane = t & 63, wv = t >> 6;
    int i = blockIdx.x * 256 + t;
    int v = (i < N) ? deg[i] : 0;
    int incl = v;
    for (int off = 1; off < 64; off <<= 1) {
        int u = __shfl_up(incl, off);
        if (lane >= off) incl += u;
    }
    __shared__ int wsum[4];
    if (lane == 63) wsum[wv] = incl;
    __syncthreads();
    int offset = partx[blockIdx.x];
    for (int w = 0; w < wv; ++w) offset += wsum[w];
    int excl = offset + incl - v;
    if (i < N) rowptr[i] = excl;
    if (i == N - 1) rowptr[N] = excl + v;
}

__global__ void copy_int_kernel(const int* __restrict__ a, int* __restrict__ b, int n) {
    int t = blockIdx.x * blockDim.x + threadIdx.x;
    if (t < n) b[t] = a[t];
}

__global__ void scatter_kernel(const int* __restrict__ src, const int* __restrict__ dst, int E,
                               int* __restrict__ cursor, int* __restrict__ colsrc) {
    int t = blockIdx.x * blockDim.x + threadIdx.x;
    if (t < E) {
        int p = atomicAdd(&cursor[dst[t]], 1);
        colsrc[p] = src[t];
    }
}

// ---------------- fused GIN layer ----------------
// One block = 64 nodes. Phase A: feature-parallel gather (lane=feature),
// z rows -> LDS (stride 65, 2-way bank alias = free). Phase B: node-parallel
// MLP (lane=node), weights via AS4 scalar loads (SGPR fmac operand), each of
// the 4 waves owns a 16-wide j-chunk. Output goes back through LDS so global
// stores are coalesced feature-parallel rows.
template<int IND, bool RELU_OUT>
__global__ __launch_bounds__(256, 4)
void gin_layer_kernel(const float* __restrict__ hin, const int* __restrict__ rowptr,
                      const int* __restrict__ colsrc,
                      const float* __restrict__ Wa, const float* __restrict__ ba,
                      const float* __restrict__ Wb, const float* __restrict__ bb,
                      float* __restrict__ hout, int N)
{
    __shared__ float zbuf[64 * 65];
    __shared__ float t1buf[64 * 65];

    const int tid = threadIdx.x;
    const int lane = tid & 63;
    const int wv = tid >> 6;
    const int flane = lane & (IND - 1);
    const int tile0 = blockIdx.x * 64;

    // ---- Phase A: gather (wave wv handles nodes tile0+16wv .. +15) ----
    for (int i = 0; i < 16; ++i) {
        int ln = wv * 16 + i;
        int node = tile0 + ln;
        float acc = 0.f;
        int e0 = 0, e1 = 0;
        if (node < N) {
            acc = hin[(size_t)node * IND + flane];
            e0 = rowptr[node];
            e1 = rowptr[node + 1];
        }
        for (int base = e0; base < e1; base += 64) {
            int ec = min(64, e1 - base);
            int sidx = (base + lane < e1) ? colsrc[base + lane] : 0;
            int k = 0;
            for (; k + 3 < ec; k += 4) {
                int s0 = __shfl(sidx, k), s1 = __shfl(sidx, k + 1),
                    s2 = __shfl(sidx, k + 2), s3 = __shfl(sidx, k + 3);
                float v0 = hin[(size_t)s0 * IND + flane];
                float v1 = hin[(size_t)s1 * IND + flane];
                float v2 = hin[(size_t)s2 * IND + flane];
                float v3 = hin[(size_t)s3 * IND + flane];
                acc += v0 + v1 + v2 + v3;
            }
            for (; k < ec; ++k) {
                int s0 = __shfl(sidx, k);
                acc += hin[(size_t)s0 * IND + flane];
            }
        }
        if (lane < IND) zbuf[ln * 65 + lane] = acc;
    }
    __syncthreads();

    // ---- Phase B: MLP, lane = node, wave wv owns j in [16wv, 16wv+16) ----
    cfp cwa = to_const(Wa);
    cfp cwb = to_const(Wb);
    cfp cba = to_const(ba);
    cfp cbb = to_const(bb);
    const int jbase = wv * 16;

    float acc1[16];
    #pragma unroll
    for (int jj = 0; jj < 16; ++jj) acc1[jj] = cba[jbase + jj];
    #pragma unroll 4
    for (int k = 0; k < IND; ++k) {
        float zk = zbuf[lane * 65 + k];
        #pragma unroll
        for (int jj = 0; jj < 16; ++jj)
            acc1[jj] = fmaf(zk, cwa[k * HD + jbase + jj], acc1[jj]);
    }
    #pragma unroll
    for (int jj = 0; jj < 16; ++jj) {
        float v = fmaxf(acc1[jj], 0.f);
        t1buf[lane * 65 + jbase + jj] = v;
    }
    __syncthreads();

    float acc2[16];
    #pragma unroll
    for (int jj = 0; jj < 16; ++jj) acc2[jj] = cbb[jbase + jj];
    #pragma unroll 4
    for (int k = 0; k < HD; ++k) {
        float tk = t1buf[lane * 65 + k];
        #pragma unroll
        for (int jj = 0; jj < 16; ++jj)
            acc2[jj] = fmaf(tk, cwb[k * HD + jbase + jj], acc2[jj]);
    }
    __syncthreads();  // everyone done reading zbuf/t1buf; reuse zbuf for output
    #pragma unroll
    for (int jj = 0; jj < 16; ++jj) {
        float v = acc2[jj];
        if (RELU_OUT) v = fmaxf(v, 0.f);
        zbuf[lane * 65 + jbase + jj] = v;
    }
    __syncthreads();

    // ---- coalesced store: lane = feature again ----
    for (int i = 0; i < 16; ++i) {
        int ln = wv * 16 + i;
        int node = tile0 + ln;
        if (node < N) hout[(size_t)node * HD + lane] = zbuf[ln * 65 + lane];
    }
}

// ---------------- global mean pool (stage 1: partial sums) ----------------
__global__ void pool_kernel(const float* __restrict__ h, const int* __restrict__ batch,
                            float* __restrict__ pool, float* __restrict__ cnt, int N) {
    int lane = threadIdx.x;  // 64 threads
    int nblk = gridDim.x;
    int per = (N + nblk - 1) / nblk;
    int lo = blockIdx.x * per, hi = min(N, lo + per);
    if (lo >= hi) return;
    int cur = batch[lo];
    float acc = 0.f, c = 0.f;
    for (int n = lo; n < hi; ++n) {
        int b = batch[n];
        if (b != cur) {
            atomicAdd(&pool[cur * HD + lane], acc);
            if (lane == 0) atomicAdd(&cnt[cur], c);
            acc = 0.f; c = 0.f; cur = b;
        }
        acc += h[(size_t)n * HD + lane];
        c += 1.f;
    }
    atomicAdd(&pool[cur * HD + lane], acc);
    if (lane == 0) atomicAdd(&cnt[cur], c);
}

// ---------------- mean + linear head ----------------
__global__ void final_kernel(const float* __restrict__ pool, const float* __restrict__ cnt,
                             const float* __restrict__ lin_w, const float* __restrict__ lin_b,
                             float* __restrict__ out, int B) {
    int b = blockIdx.x;
    int lane = threadIdx.x;
    float c = fmaxf(cnt[b], 1.f);
    float v = pool[b * HD + lane] / c * lin_w[lane];
    for (int off = 32; off > 0; off >>= 1) v += __shfl_down(v, off);
    if (lane == 0) out[b] = v + lin_b[0];
}

extern "C" void kernel_launch(void* const* d_in, const int* in_sizes, int n_in,
                              void* d_out, int out_size, void* d_ws, size_t ws_size,
                              hipStream_t stream)
{
    const float* x   = (const float*)d_in[0];
    const float* pos = (const float*)d_in[1];
    const int*  eidx = (const int*)d_in[2];
    const int* batch = (const int*)d_in[3];
    const float* W1f = (const float*)d_in[4];
    const float* W1r = (const float*)d_in[5];
    const float* b1  = (const float*)d_in[6];
    const float* W2  = (const float*)d_in[7];
    const float* b2  = (const float*)d_in[8];
    const float* lw  = (const float*)d_in[9];
    const float* lb  = (const float*)d_in[10];

    int N = in_sizes[3];
    int E = in_sizes[2] / 2;
    int B = out_size;
    const int* src = eidx;
    const int* dst = eidx + E;

    char* ws = (char*)d_ws;
    size_t off = 0;
    auto alloc = [&](size_t bytes) -> void* {
        void* p = ws + off;
        off += (bytes + 255) & ~(size_t)255;
        return p;
    };
    float* bufA   = (float*)alloc((size_t)N * HD * 4);
    float* bufB   = (float*)alloc((size_t)N * HD * 4);
    int*   rowptr = (int*)  alloc((size_t)(N + 1) * 4);
    int*   cursor = (int*)  alloc((size_t)N * 4);
    int*   colsrc = (int*)  alloc((size_t)E * 4);
    float* pool   = (float*)alloc((size_t)B * HD * 4);
    float* cnt    = (float*)alloc((size_t)B * 4);
    int*   part   = (int*)  alloc(256 * 4);
    int*   partx  = (int*)  alloc(256 * 4);

    hipMemsetAsync(cursor, 0, (size_t)N * 4, stream);
    hipMemsetAsync(pool, 0, (size_t)B * HD * 4, stream);
    hipMemsetAsync(cnt, 0, (size_t)B * 4, stream);

    int nPart = (N + 255) / 256;

    build_h0_kernel<<<(N * INF + 255) / 256, 256, 0, stream>>>(x, pos, bufA, N);
    hist_kernel<<<(E + 255) / 256, 256, 0, stream>>>(dst, E, cursor);
    scan1_kernel<<<nPart, 256, 0, stream>>>(cursor, part, N);
    scan2_kernel<<<1, 256, 0, stream>>>(part, partx, nPart);
    scan3_kernel<<<nPart, 256, 0, stream>>>(cursor, partx, rowptr, N);
    copy_int_kernel<<<(N + 255) / 256, 256, 0, stream>>>(rowptr, cursor, N);
    scatter_kernel<<<(E + 255) / 256, 256, 0, stream>>>(src, dst, E, cursor, colsrc);

    const int gblocks = (N + 63) / 64;
    gin_layer_kernel<INF, true><<<gblocks, 256, 0, stream>>>(bufA, rowptr, colsrc,
                                                             W1f, b1, W2, b2, bufB, N);
    float* cur_in = bufB;
    float* cur_out = bufA;
    for (int l = 1; l < NL; ++l) {
        const float* Wa = W1r + (size_t)(l - 1) * HD * HD;
        const float* ba = b1 + l * HD;
        const float* Wb = W2 + (size_t)l * HD * HD;
        const float* bb = b2 + l * HD;
        if (l < NL - 1)
            gin_layer_kernel<HD, true><<<gblocks, 256, 0, stream>>>(cur_in, rowptr, colsrc,
                                                                    Wa, ba, Wb, bb, cur_out, N);
        else
            gin_layer_kernel<HD, false><<<gblocks, 256, 0, stream>>>(cur_in, rowptr, colsrc,
                                                                     Wa, ba, Wb, bb, cur_out, N);
        float* tmp = cur_in; cur_in = cur_out; cur_out = tmp;
    }
    pool_kernel<<<512, 64, 0, stream>>>(cur_in, batch, pool, cnt, N);
    final_kernel<<<B, 64, 0, stream>>>(pool, cnt, lw, lb, (float*)d_out, B);
}

// Round 3
// 437.061 us; speedup vs baseline: 2.1622x; 2.1622x over previous
//
#include <hip/hip_runtime.h>
#include <stdint.h>

#define NF 29
#define HD 64
#define NL 7

typedef __attribute__((ext_vector_type(8))) __bf16 bf16x8;
typedef __attribute__((ext_vector_type(4))) float floatx4;

// fp32 -> bf16 bits, round-to-nearest-even
__device__ __forceinline__ unsigned short f2bf(float x) {
    unsigned u = __float_as_uint(x);
    unsigned r = (u + 0x7fffu + ((u >> 16) & 1u)) >> 16;
    return (unsigned short)r;
}
__device__ __forceinline__ unsigned pack_bf2(float x, float y) {
    return (unsigned)f2bf(x) | ((unsigned)f2bf(y) << 16);
}

// ---------------- h0 = concat(x, pos) -> bf16 ----------------
__global__ void build_h0_kernel(const float* __restrict__ x, const float* __restrict__ pos,
                                unsigned short* __restrict__ h0, int N) {
    int t = blockIdx.x * blockDim.x + threadIdx.x;
    if (t >= N * 32) return;
    int n = t >> 5, f = t & 31;
    float v = (f < NF) ? x[n * NF + f] : pos[n * 3 + (f - NF)];
    h0[t] = f2bf(v);
}

// ---------------- CSR build ----------------
__global__ void hist_kernel(const int* __restrict__ dst, int E, int* __restrict__ deg) {
    int t = blockIdx.x * blockDim.x + threadIdx.x;
    if (t < E) atomicAdd(&deg[dst[t]], 1);
}

__global__ void scan1_kernel(const int* __restrict__ deg, int* __restrict__ part, int N) {
    int t = threadIdx.x;
    int i = blockIdx.x * 256 + t;
    int v = (i < N) ? deg[i] : 0;
    for (int off = 32; off > 0; off >>= 1) v += __shfl_down(v, off);
    __shared__ int ws[4];
    if ((t & 63) == 0) ws[t >> 6] = v;
    __syncthreads();
    if (t == 0) part[blockIdx.x] = ws[0] + ws[1] + ws[2] + ws[3];
}

__global__ void scan2_kernel(const int* __restrict__ part, int* __restrict__ partx, int nPart) {
    __shared__ int s[256];
    int t = threadIdx.x;
    s[t] = (t < nPart) ? part[t] : 0;
    __syncthreads();
    for (int off = 1; off < 256; off <<= 1) {
        int v = (t >= off) ? s[t - off] : 0;
        __syncthreads();
        s[t] += v;
        __syncthreads();
    }
    partx[t] = (t == 0) ? 0 : s[t - 1];
}

__global__ void scan3_kernel(const int* __restrict__ deg, const int* __restrict__ partx,
                             int* __restrict__ rowptr, int N) {
    int t = threadIdx.x;
    int lane = t & 63, wv = t >> 6;
    int i = blockIdx.x * 256 + t;
    int v = (i < N) ? deg[i] : 0;
    int incl = v;
    for (int off = 1; off < 64; off <<= 1) {
        int u = __shfl_up(incl, off);
        if (lane >= off) incl += u;
    }
    __shared__ int wsum[4];
    if (lane == 63) wsum[wv] = incl;
    __syncthreads();
    int offset = partx[blockIdx.x];
    for (int w = 0; w < wv; ++w) offset += wsum[w];
    int excl = offset + incl - v;
    if (i < N) rowptr[i] = excl;
    if (i == N - 1) rowptr[N] = excl + v;
}

__global__ void copy_int_kernel(const int* __restrict__ a, int* __restrict__ b, int n) {
    int t = blockIdx.x * blockDim.x + threadIdx.x;
    if (t < n) b[t] = a[t];
}

__global__ void scatter_kernel(const int* __restrict__ src, const int* __restrict__ dst, int E,
                               int* __restrict__ cursor, int* __restrict__ colsrc) {
    int t = blockIdx.x * blockDim.x + threadIdx.x;
    if (t < E) {
        int p = atomicAdd(&cursor[dst[t]], 1);
        colsrc[p] = src[t];
    }
}

// ---------------- fused GIN layer: bf16 gather + MFMA MLP ----------------
// Block = 512 threads (8 waves) = 64-node tile.
// Gather: lane = (slot, featpair); one u32 load per lane covers NS edges/issue.
// MLP: z(64xIND bf16) @ Wa -> relu -> @ Wb via mfma_f32_16x16x32_bf16.
// Wave w: node stripe (w&3)*16, j-tiles {2*(w>>2), 2*(w>>2)+1}.
template<int IND, bool RELU_OUT>
__global__ __launch_bounds__(512, 6)
void gin_layer_kernel(const unsigned short* __restrict__ hin,
                      const int* __restrict__ rowptr, const int* __restrict__ colsrc,
                      const float* __restrict__ Wa, const float* __restrict__ ba,
                      const float* __restrict__ Wb, const float* __restrict__ bb,
                      unsigned short* __restrict__ hout, int N)
{
    constexpr int LDW = 72;        // padded bf16 row stride (144 B, 16B-aligned)
    constexpr int W2 = IND / 2;    // u32 per input row
    constexpr int NS = 64 / W2;    // edge slots per wave

    __shared__ __align__(16) unsigned short zbuf[64 * LDW];
    __shared__ __align__(16) unsigned short t1buf[64 * LDW];
    __shared__ __align__(16) unsigned short waT[64 * LDW];
    __shared__ __align__(16) unsigned short wbT[64 * LDW];

    const int tid = threadIdx.x;
    const int lane = tid & 63;
    const int w = tid >> 6;
    const int tile0 = blockIdx.x * 64;

    // ---- stage W^T into LDS as bf16 (B-operand wants k contiguous per column) ----
    for (int i = tid; i < IND * 64; i += 512) {
        int k = i >> 6, j = i & 63;
        waT[j * LDW + k] = f2bf(Wa[i]);
    }
    for (int i = tid; i < 64 * 64; i += 512) {
        int k = i >> 6, j = i & 63;
        wbT[j * LDW + k] = f2bf(Wb[i]);
    }

    // ---- gather: wave w owns local nodes [8w, 8w+8) ----
    const int f2 = lane & (W2 - 1);
    const int slot = lane / W2;
    const uint32_t* hin32 = (const uint32_t*)hin;
    uint32_t* z32 = (uint32_t*)zbuf;

    for (int i = 0; i < 8; ++i) {
        int local = w * 8 + i;
        int node = tile0 + local;
        float ax = 0.f, ay = 0.f;
        int e0 = 0, e1 = 0;
        if (node < N) { e0 = rowptr[node]; e1 = rowptr[node + 1]; }
        if (node < N && slot == 0) {   // self term
            uint32_t u = hin32[(size_t)node * W2 + f2];
            ax = __uint_as_float(u << 16);
            ay = __uint_as_float(u & 0xffff0000u);
        }
        int e = e0 + slot;
        for (; e + 3 * NS < e1; e += 4 * NS) {   // 4 independent row loads in flight
            int s0 = colsrc[e], s1 = colsrc[e + NS], s2 = colsrc[e + 2 * NS], s3 = colsrc[e + 3 * NS];
            uint32_t u0 = hin32[(size_t)s0 * W2 + f2];
            uint32_t u1 = hin32[(size_t)s1 * W2 + f2];
            uint32_t u2 = hin32[(size_t)s2 * W2 + f2];
            uint32_t u3 = hin32[(size_t)s3 * W2 + f2];
            ax += __uint_as_float(u0 << 16); ay += __uint_as_float(u0 & 0xffff0000u);
            ax += __uint_as_float(u1 << 16); ay += __uint_as_float(u1 & 0xffff0000u);
            ax += __uint_as_float(u2 << 16); ay += __uint_as_float(u2 & 0xffff0000u);
            ax += __uint_as_float(u3 << 16); ay += __uint_as_float(u3 & 0xffff0000u);
        }
        for (; e < e1; e += NS) {
            int s0 = colsrc[e];
            uint32_t u0 = hin32[(size_t)s0 * W2 + f2];
            ax += __uint_as_float(u0 << 16); ay += __uint_as_float(u0 & 0xffff0000u);
        }
        // reduce partial sums across edge slots
        if (NS == 4) { ax += __shfl_xor(ax, 16); ay += __shfl_xor(ay, 16); }
        ax += __shfl_xor(ax, 32); ay += __shfl_xor(ay, 32);
        if (slot == 0) z32[local * (LDW / 2) + f2] = pack_bf2(ax, ay);
    }
    __syncthreads();

    // ---- MFMA MLP ----
    const int n0 = lane & 15, quad = lane >> 4;
    const int stripe = w & 3, jhalf = w >> 2;
    const int row0 = stripe * 16;
    const int jt0 = jhalf * 2, jt1 = jhalf * 2 + 1;

    floatx4 c0, c1;
    {
        float b0v = ba[jt0 * 16 + n0], b1v = ba[jt1 * 16 + n0];
        c0 = (floatx4){b0v, b0v, b0v, b0v};
        c1 = (floatx4){b1v, b1v, b1v, b1v};
    }
    #pragma unroll
    for (int kk = 0; kk < IND / 32; ++kk) {
        bf16x8 a  = *(const bf16x8*)&zbuf[(row0 + n0) * LDW + kk * 32 + quad * 8];
        bf16x8 bf0 = *(const bf16x8*)&waT[(jt0 * 16 + n0) * LDW + kk * 32 + quad * 8];
        bf16x8 bf1 = *(const bf16x8*)&waT[(jt1 * 16 + n0) * LDW + kk * 32 + quad * 8];
        c0 = __builtin_amdgcn_mfma_f32_16x16x32_bf16(a, bf0, c0, 0, 0, 0);
        c1 = __builtin_amdgcn_mfma_f32_16x16x32_bf16(a, bf1, c1, 0, 0, 0);
    }
    #pragma unroll
    for (int r = 0; r < 4; ++r) {   // relu + C-layout -> t1buf (row = node, col = j)
        int row = row0 + quad * 4 + r;
        t1buf[row * LDW + jt0 * 16 + n0] = f2bf(fmaxf(c0[r], 0.f));
        t1buf[row * LDW + jt1 * 16 + n0] = f2bf(fmaxf(c1[r], 0.f));
    }
    __syncthreads();

    {
        float b0v = bb[jt0 * 16 + n0], b1v = bb[jt1 * 16 + n0];
        c0 = (floatx4){b0v, b0v, b0v, b0v};
        c1 = (floatx4){b1v, b1v, b1v, b1v};
    }
    #pragma unroll
    for (int kk = 0; kk < 2; ++kk) {
        bf16x8 a  = *(const bf16x8*)&t1buf[(row0 + n0) * LDW + kk * 32 + quad * 8];
        bf16x8 bf0 = *(const bf16x8*)&wbT[(jt0 * 16 + n0) * LDW + kk * 32 + quad * 8];
        bf16x8 bf1 = *(const bf16x8*)&wbT[(jt1 * 16 + n0) * LDW + kk * 32 + quad * 8];
        c0 = __builtin_amdgcn_mfma_f32_16x16x32_bf16(a, bf0, c0, 0, 0, 0);
        c1 = __builtin_amdgcn_mfma_f32_16x16x32_bf16(a, bf1, c1, 0, 0, 0);
    }
    __syncthreads();   // all t1/zbuf readers done; zbuf reusable as output staging
    #pragma unroll
    for (int r = 0; r < 4; ++r) {
        int row = row0 + quad * 4 + r;
        float v0 = c0[r], v1 = c1[r];
        if (RELU_OUT) { v0 = fmaxf(v0, 0.f); v1 = fmaxf(v1, 0.f); }
        zbuf[row * LDW + jt0 * 16 + n0] = f2bf(v0);
        zbuf[row * LDW + jt1 * 16 + n0] = f2bf(v1);
    }
    __syncthreads();

    // ---- coalesced bf16 store (u32 granules) ----
    uint32_t* out32 = (uint32_t*)hout;
    for (int i = tid; i < 64 * 32; i += 512) {
        int nl = i >> 5, d = i & 31;
        int node = tile0 + nl;
        if (node < N) out32[(size_t)node * 32 + d] = z32[nl * (LDW / 2) + d];
    }
}

// ---------------- global mean pool (partial sums over sorted batch) ----------------
__global__ void pool_kernel(const unsigned short* __restrict__ h, const int* __restrict__ batch,
                            float* __restrict__ pool, float* __restrict__ cnt, int N) {
    int lane = threadIdx.x;  // 64 threads
    int nblk = gridDim.x;
    int per = (N + nblk - 1) / nblk;
    int lo = blockIdx.x * per, hi = min(N, lo + per);
    if (lo >= hi) return;
    int cur = batch[lo];
    float acc = 0.f, c = 0.f;
    for (int n = lo; n < hi; ++n) {
        int b = batch[n];
        if (b != cur) {
            atomicAdd(&pool[cur * HD + lane], acc);
            if (lane == 0) atomicAdd(&cnt[cur], c);
            acc = 0.f; c = 0.f; cur = b;
        }
        acc += __uint_as_float((uint32_t)h[(size_t)n * HD + lane] << 16);
        c += 1.f;
    }
    atomicAdd(&pool[cur * HD + lane], acc);
    if (lane == 0) atomicAdd(&cnt[cur], c);
}

// ---------------- mean + linear head ----------------
__global__ void final_kernel(const float* __restrict__ pool, const float* __restrict__ cnt,
                             const float* __restrict__ lin_w, const float* __restrict__ lin_b,
                             float* __restrict__ out, int B) {
    int b = blockIdx.x;
    int lane = threadIdx.x;
    float c = fmaxf(cnt[b], 1.f);
    float v = pool[b * HD + lane] / c * lin_w[lane];
    for (int off = 32; off > 0; off >>= 1) v += __shfl_down(v, off);
    if (lane == 0) out[b] = v + lin_b[0];
}

extern "C" void kernel_launch(void* const* d_in, const int* in_sizes, int n_in,
                              void* d_out, int out_size, void* d_ws, size_t ws_size,
                              hipStream_t stream)
{
    const float* x   = (const float*)d_in[0];
    const float* pos = (const float*)d_in[1];
    const int*  eidx = (const int*)d_in[2];
    const int* batch = (const int*)d_in[3];
    const float* W1f = (const float*)d_in[4];
    const float* W1r = (const float*)d_in[5];
    const float* b1  = (const float*)d_in[6];
    const float* W2  = (const float*)d_in[7];
    const float* b2  = (const float*)d_in[8];
    const float* lw  = (const float*)d_in[9];
    const float* lb  = (const float*)d_in[10];

    int N = in_sizes[3];
    int E = in_sizes[2] / 2;
    int B = out_size;
    const int* src = eidx;
    const int* dst = eidx + E;

    char* ws = (char*)d_ws;
    size_t off = 0;
    auto alloc = [&](size_t bytes) -> void* {
        void* p = ws + off;
        off += (bytes + 255) & ~(size_t)255;
        return p;
    };
    unsigned short* bufA = (unsigned short*)alloc((size_t)N * HD * 2);
    unsigned short* bufB = (unsigned short*)alloc((size_t)N * HD * 2);
    int*   rowptr = (int*)  alloc((size_t)(N + 1) * 4);
    int*   cursor = (int*)  alloc((size_t)N * 4);
    int*   colsrc = (int*)  alloc((size_t)E * 4);
    float* pool   = (float*)alloc((size_t)B * HD * 4);
    float* cnt    = (float*)alloc((size_t)B * 4);
    int*   part   = (int*)  alloc(256 * 4);
    int*   partx  = (int*)  alloc(256 * 4);

    hipMemsetAsync(cursor, 0, (size_t)N * 4, stream);
    hipMemsetAsync(pool, 0, (size_t)B * HD * 4, stream);
    hipMemsetAsync(cnt, 0, (size_t)B * 4, stream);

    int nPart = (N + 255) / 256;

    build_h0_kernel<<<(N * 32 + 255) / 256, 256, 0, stream>>>(x, pos, bufA, N);
    hist_kernel<<<(E + 255) / 256, 256, 0, stream>>>(dst, E, cursor);
    scan1_kernel<<<nPart, 256, 0, stream>>>(cursor, part, N);
    scan2_kernel<<<1, 256, 0, stream>>>(part, partx, nPart);
    scan3_kernel<<<nPart, 256, 0, stream>>>(cursor, partx, rowptr, N);
    copy_int_kernel<<<(N + 255) / 256, 256, 0, stream>>>(rowptr, cursor, N);
    scatter_kernel<<<(E + 255) / 256, 256, 0, stream>>>(src, dst, E, cursor, colsrc);

    const int gblocks = (N + 63) / 64;
    gin_layer_kernel<32, true><<<gblocks, 512, 0, stream>>>(bufA, rowptr, colsrc,
                                                            W1f, b1, W2, b2, bufB, N);
    unsigned short* cur_in = bufB;
    unsigned short* cur_out = bufA;
    for (int l = 1; l < NL; ++l) {
        const float* Wa = W1r + (size_t)(l - 1) * HD * HD;
        const float* ba = b1 + l * HD;
        const float* Wb = W2 + (size_t)l * HD * HD;
        const float* bb = b2 + l * HD;
        if (l < NL - 1)
            gin_layer_kernel<HD, true><<<gblocks, 512, 0, stream>>>(cur_in, rowptr, colsrc,
                                                                    Wa, ba, Wb, bb, cur_out, N);
        else
            gin_layer_kernel<HD, false><<<gblocks, 512, 0, stream>>>(cur_in, rowptr, colsrc,
                                                                     Wa, ba, Wb, bb, cur_out, N);
        unsigned short* tmp = cur_in; cur_in = cur_out; cur_out = tmp;
    }
    pool_kernel<<<512, 64, 0, stream>>>(cur_in, batch, pool, cnt, N);
    final_kernel<<<B, 64, 0, stream>>>(pool, cnt, lw, lb, (float*)d_out, B);
}

// Round 4
// 347.111 us; speedup vs baseline: 2.7225x; 1.2591x over previous
//
#include <hip/hip_runtime.h>
#include <stdint.h>

#define NF 29
#define HD 64
#define NL 7
#define LDW 72   // padded bf16 row stride (144 B, 16B-aligned)

typedef __attribute__((ext_vector_type(8))) __bf16 bf16x8;
typedef __attribute__((ext_vector_type(4))) float floatx4;

// fp32 -> bf16 bits, round-to-nearest-even
__device__ __forceinline__ unsigned short f2bf(float x) {
    unsigned u = __float_as_uint(x);
    unsigned r = (u + 0x7fffu + ((u >> 16) & 1u)) >> 16;
    return (unsigned short)r;
}
__device__ __forceinline__ unsigned pack_bf2(float x, float y) {
    return (unsigned)f2bf(x) | ((unsigned)f2bf(y) << 16);
}
__device__ __forceinline__ float bflo(uint32_t u) { return __uint_as_float(u << 16); }
__device__ __forceinline__ float bfhi(uint32_t u) { return __uint_as_float(u & 0xffff0000u); }

// ---------------- h0 = concat(x, pos) -> bf16 ----------------
__global__ void build_h0_kernel(const float* __restrict__ x, const float* __restrict__ pos,
                                unsigned short* __restrict__ h0, int N) {
    int t = blockIdx.x * blockDim.x + threadIdx.x;
    if (t >= N * 32) return;
    int n = t >> 5, f = t & 31;
    float v = (f < NF) ? x[n * NF + f] : pos[n * 3 + (f - NF)];
    h0[t] = f2bf(v);
}

// ---------------- weights: fp32 -> transposed, padded bf16 (once per launch) ----------------
// wpk layout per layer l: [l*2+0] = Wa^T (64 x LDW, waT[j*LDW+k] = Wa[k*64+j], pad k>=IND -> 0)
//                         [l*2+1] = Wb^T
__global__ void prep_weights_kernel(const float* __restrict__ W1f, const float* __restrict__ W1r,
                                    const float* __restrict__ W2, unsigned short* __restrict__ wpk) {
    const int PER_M = 64 * LDW;  // 4608
    int t = blockIdx.x * blockDim.x + threadIdx.x;
    if (t >= NL * 2 * PER_M) return;
    int l = t / (2 * PER_M);
    int r = t - l * 2 * PER_M;
    int m = r / PER_M;
    int q = r - m * PER_M;
    int j = q / LDW, k = q - j * LDW;
    float v = 0.f;
    if (m == 0) {
        int ind = (l == 0) ? 32 : 64;
        if (k < ind) v = (l == 0) ? W1f[k * 64 + j]
                                  : W1r[(size_t)(l - 1) * 4096 + (size_t)k * 64 + j];
    } else {
        if (k < 64) v = W2[(size_t)l * 4096 + (size_t)k * 64 + j];
    }
    wpk[t] = f2bf(v);
}

// ---------------- CSR build ----------------
__global__ void hist_kernel(const int* __restrict__ dst, int E, int* __restrict__ deg) {
    int t = blockIdx.x * blockDim.x + threadIdx.x;
    if (t < E) atomicAdd(&deg[dst[t]], 1);
}

__global__ void scan1_kernel(const int* __restrict__ deg, int* __restrict__ part, int N) {
    int t = threadIdx.x;
    int i = blockIdx.x * 256 + t;
    int v = (i < N) ? deg[i] : 0;
    for (int off = 32; off > 0; off >>= 1) v += __shfl_down(v, off);
    __shared__ int ws[4];
    if ((t & 63) == 0) ws[t >> 6] = v;
    __syncthreads();
    if (t == 0) part[blockIdx.x] = ws[0] + ws[1] + ws[2] + ws[3];
}

__global__ void scan2_kernel(const int* __restrict__ part, int* __restrict__ partx, int nPart) {
    __shared__ int s[256];
    int t = threadIdx.x;
    s[t] = (t < nPart) ? part[t] : 0;
    __syncthreads();
    for (int off = 1; off < 256; off <<= 1) {
        int v = (t >= off) ? s[t - off] : 0;
        __syncthreads();
        s[t] += v;
        __syncthreads();
    }
    partx[t] = (t == 0) ? 0 : s[t - 1];
}

__global__ void scan3_kernel(const int* __restrict__ deg, const int* __restrict__ partx,
                             int* __restrict__ rowptr, int N) {
    int t = threadIdx.x;
    int lane = t & 63, wv = t >> 6;
    int i = blockIdx.x * 256 + t;
    int v = (i < N) ? deg[i] : 0;
    int incl = v;
    for (int off = 1; off < 64; off <<= 1) {
        int u = __shfl_up(incl, off);
        if (lane >= off) incl += u;
    }
    __shared__ int wsum[4];
    if (lane == 63) wsum[wv] = incl;
    __syncthreads();
    int offset = partx[blockIdx.x];
    for (int w = 0; w < wv; ++w) offset += wsum[w];
    int excl = offset + incl - v;
    if (i < N) rowptr[i] = excl;
    if (i == N - 1) rowptr[N] = excl + v;
}

__global__ void copy_int_kernel(const int* __restrict__ a, int* __restrict__ b, int n) {
    int t = blockIdx.x * blockDim.x + threadIdx.x;
    if (t < n) b[t] = a[t];
}

__global__ void scatter_kernel(const int* __restrict__ src, const int* __restrict__ dst, int E,
                               int* __restrict__ cursor, int* __restrict__ colsrc) {
    int t = blockIdx.x * blockDim.x + threadIdx.x;
    if (t < E) {
        int p = atomicAdd(&cursor[dst[t]], 1);
        colsrc[p] = src[t];
    }
}

// ---------------- fused GIN layer: wide-load gather + MFMA MLP ----------------
// Block = 512 threads (8 waves) = 64-node tile.
// Gather: lane = (g = lane>>3 node sub-idx, f4 chunk). Each 8-lane group owns one
// node and accumulates uint4 (16B) row chunks: one wave instr = 8 rows in flight,
// 4-deep unroll, no cross-group reduce.
// MLP: z @ Wa -> relu -> @ Wb via mfma_f32_16x16x32_bf16 (unchanged from r3).
template<int IND, bool RELU_OUT>
__global__ __launch_bounds__(512, 8)
void gin_layer_kernel(const unsigned short* __restrict__ hin,
                      const int* __restrict__ rowptr, const int* __restrict__ colsrc,
                      const unsigned short* __restrict__ wAT, const unsigned short* __restrict__ wBT,
                      const float* __restrict__ ba, const float* __restrict__ bb,
                      unsigned short* __restrict__ hout, int N)
{
    __shared__ __align__(16) unsigned short zbuf[64 * LDW];
    __shared__ __align__(16) unsigned short t1buf[64 * LDW];
    __shared__ __align__(16) unsigned short waT[64 * LDW];
    __shared__ __align__(16) unsigned short wbT[64 * LDW];

    const int tid = threadIdx.x;
    const int lane = tid & 63;
    const int w = tid >> 6;
    const int tile0 = blockIdx.x * 64;

    // ---- stage pre-packed bf16 weights: pure uint4 memcpy ----
    {
        const uint4* a4 = (const uint4*)wAT;
        const uint4* b4 = (const uint4*)wBT;
        uint4* da = (uint4*)waT;
        uint4* db = (uint4*)wbT;
        for (int i = tid; i < 64 * LDW / 8; i += 512) { da[i] = a4[i]; db[i] = b4[i]; }
    }

    // ---- gather: group g (8 lanes) owns node tile0 + w*8 + g ----
    const uint4* hin4 = (const uint4*)hin;
    const int g = lane >> 3;
    const int node = tile0 + w * 8 + g;

    int rp;
    {
        int idx = tile0 + w * 8 + (lane < 9 ? lane : 8);
        if (idx > N) idx = N;
        rp = rowptr[idx];
    }
    int e0 = __shfl(rp, g);
    int e1 = __shfl(rp, g + 1);
    if (node >= N) { e0 = 0; e1 = 0; }

    float acc[8] = {0.f, 0.f, 0.f, 0.f, 0.f, 0.f, 0.f, 0.f};
    auto addrow = [&](uint4 u) {
        acc[0] += bflo(u.x); acc[1] += bfhi(u.x);
        acc[2] += bflo(u.y); acc[3] += bfhi(u.y);
        acc[4] += bflo(u.z); acc[5] += bfhi(u.z);
        acc[6] += bflo(u.w); acc[7] += bfhi(u.w);
    };

    if constexpr (IND == 64) {
        const int f4 = lane & 7;                       // 8 chunks x 16B = 128B row
        if (node < N) addrow(hin4[(size_t)node * 8 + f4]);   // self term
        int e = e0;
        for (; e + 3 < e1; e += 4) {
            int s0 = colsrc[e], s1 = colsrc[e + 1], s2 = colsrc[e + 2], s3 = colsrc[e + 3];
            uint4 u0 = hin4[(size_t)s0 * 8 + f4];
            uint4 u1 = hin4[(size_t)s1 * 8 + f4];
            uint4 u2 = hin4[(size_t)s2 * 8 + f4];
            uint4 u3 = hin4[(size_t)s3 * 8 + f4];
            addrow(u0); addrow(u1); addrow(u2); addrow(u3);
        }
        for (; e < e1; ++e) addrow(hin4[(size_t)colsrc[e] * 8 + f4]);
        uint4 pk;
        pk.x = pack_bf2(acc[0], acc[1]); pk.y = pack_bf2(acc[2], acc[3]);
        pk.z = pack_bf2(acc[4], acc[5]); pk.w = pack_bf2(acc[6], acc[7]);
        *(uint4*)&zbuf[(w * 8 + g) * LDW + f4 * 8] = pk;
    } else {  // IND == 32: 4 chunks/row; group splits into p = 0/1 edge-pair lanes
        const int p = (lane >> 2) & 1;
        const int f4 = lane & 3;
        if (node < N && p == 0) addrow(hin4[(size_t)node * 4 + f4]);  // self once
        int e = e0 + p;
        for (; e + 3 < e1; e += 4) {
            int s0 = colsrc[e], s1 = colsrc[e + 2];
            uint4 u0 = hin4[(size_t)s0 * 4 + f4];
            uint4 u1 = hin4[(size_t)s1 * 4 + f4];
            addrow(u0); addrow(u1);
        }
        while (e < e1) { addrow(hin4[(size_t)colsrc[e] * 4 + f4]); e += 2; }
        #pragma unroll
        for (int i = 0; i < 8; ++i) acc[i] += __shfl_xor(acc[i], 4);
        if (p == 0) {
            uint4 pk;
            pk.x = pack_bf2(acc[0], acc[1]); pk.y = pack_bf2(acc[2], acc[3]);
            pk.z = pack_bf2(acc[4], acc[5]); pk.w = pack_bf2(acc[6], acc[7]);
            *(uint4*)&zbuf[(w * 8 + g) * LDW + f4 * 8] = pk;
        }
    }
    __syncthreads();

    // ---- MFMA MLP ----
    const int n0 = lane & 15, quad = lane >> 4;
    const int stripe = w & 3, jhalf = w >> 2;
    const int row0 = stripe * 16;
    const int jt0 = jhalf * 2, jt1 = jhalf * 2 + 1;

    floatx4 c0, c1;
    {
        float b0v = ba[jt0 * 16 + n0], b1v = ba[jt1 * 16 + n0];
        c0 = (floatx4){b0v, b0v, b0v, b0v};
        c1 = (floatx4){b1v, b1v, b1v, b1v};
    }
    #pragma unroll
    for (int kk = 0; kk < IND / 32; ++kk) {
        bf16x8 a   = *(const bf16x8*)&zbuf[(row0 + n0) * LDW + kk * 32 + quad * 8];
        bf16x8 br0 = *(const bf16x8*)&waT[(jt0 * 16 + n0) * LDW + kk * 32 + quad * 8];
        bf16x8 br1 = *(const bf16x8*)&waT[(jt1 * 16 + n0) * LDW + kk * 32 + quad * 8];
        c0 = __builtin_amdgcn_mfma_f32_16x16x32_bf16(a, br0, c0, 0, 0, 0);
        c1 = __builtin_amdgcn_mfma_f32_16x16x32_bf16(a, br1, c1, 0, 0, 0);
    }
    #pragma unroll
    for (int r = 0; r < 4; ++r) {
        int row = row0 + quad * 4 + r;
        t1buf[row * LDW + jt0 * 16 + n0] = f2bf(fmaxf(c0[r], 0.f));
        t1buf[row * LDW + jt1 * 16 + n0] = f2bf(fmaxf(c1[r], 0.f));
    }
    __syncthreads();

    {
        float b0v = bb[jt0 * 16 + n0], b1v = bb[jt1 * 16 + n0];
        c0 = (floatx4){b0v, b0v, b0v, b0v};
        c1 = (floatx4){b1v, b1v, b1v, b1v};
    }
    #pragma unroll
    for (int kk = 0; kk < 2; ++kk) {
        bf16x8 a   = *(const bf16x8*)&t1buf[(row0 + n0) * LDW + kk * 32 + quad * 8];
        bf16x8 br0 = *(const bf16x8*)&wbT[(jt0 * 16 + n0) * LDW + kk * 32 + quad * 8];
        bf16x8 br1 = *(const bf16x8*)&wbT[(jt1 * 16 + n0) * LDW + kk * 32 + quad * 8];
        c0 = __builtin_amdgcn_mfma_f32_16x16x32_bf16(a, br0, c0, 0, 0, 0);
        c1 = __builtin_amdgcn_mfma_f32_16x16x32_bf16(a, br1, c1, 0, 0, 0);
    }
    // zbuf free after the t1 barrier; write outputs there for a coalesced store
    #pragma unroll
    for (int r = 0; r < 4; ++r) {
        int row = row0 + quad * 4 + r;
        float v0 = c0[r], v1 = c1[r];
        if (RELU_OUT) { v0 = fmaxf(v0, 0.f); v1 = fmaxf(v1, 0.f); }
        zbuf[row * LDW + jt0 * 16 + n0] = f2bf(v0);
        zbuf[row * LDW + jt1 * 16 + n0] = f2bf(v1);
    }
    __syncthreads();

    // ---- store: 512 threads x uint4 = full 64x128B tile, fully sequential ----
    {
        int nl = tid >> 3, c4 = tid & 7;
        int nodeo = tile0 + nl;
        if (nodeo < N) {
            uint4 v = *(const uint4*)&zbuf[nl * LDW + c4 * 8];
            ((uint4*)hout)[(size_t)nodeo * 8 + c4] = v;
        }
    }
}

// ---------------- global mean pool (partial sums over sorted batch) ----------------
__global__ void pool_kernel(const unsigned short* __restrict__ h, const int* __restrict__ batch,
                            float* __restrict__ pool, float* __restrict__ cnt, int N) {
    int lane = threadIdx.x;  // 64 threads
    int nblk = gridDim.x;
    int per = (N + nblk - 1) / nblk;
    int lo = blockIdx.x * per, hi = min(N, lo + per);
    if (lo >= hi) return;
    int cur = batch[lo];
    float acc = 0.f, c = 0.f;
    for (int n = lo; n < hi; ++n) {
        int b = batch[n];
        if (b != cur) {
            atomicAdd(&pool[cur * HD + lane], acc);
            if (lane == 0) atomicAdd(&cnt[cur], c);
            acc = 0.f; c = 0.f; cur = b;
        }
        acc += __uint_as_float((uint32_t)h[(size_t)n * HD + lane] << 16);
        c += 1.f;
    }
    atomicAdd(&pool[cur * HD + lane], acc);
    if (lane == 0) atomicAdd(&cnt[cur], c);
}

// ---------------- mean + linear head ----------------
__global__ void final_kernel(const float* __restrict__ pool, const float* __restrict__ cnt,
                             const float* __restrict__ lin_w, const float* __restrict__ lin_b,
                             float* __restrict__ out, int B) {
    int b = blockIdx.x;
    int lane = threadIdx.x;
    float c = fmaxf(cnt[b], 1.f);
    float v = pool[b * HD + lane] / c * lin_w[lane];
    for (int off = 32; off > 0; off >>= 1) v += __shfl_down(v, off);
    if (lane == 0) out[b] = v + lin_b[0];
}

extern "C" void kernel_launch(void* const* d_in, const int* in_sizes, int n_in,
                              void* d_out, int out_size, void* d_ws, size_t ws_size,
                              hipStream_t stream)
{
    const float* x   = (const float*)d_in[0];
    const float* pos = (const float*)d_in[1];
    const int*  eidx = (const int*)d_in[2];
    const int* batch = (const int*)d_in[3];
    const float* W1f = (const float*)d_in[4];
    const float* W1r = (const float*)d_in[5];
    const float* b1  = (const float*)d_in[6];
    const float* W2  = (const float*)d_in[7];
    const float* b2  = (const float*)d_in[8];
    const float* lw  = (const float*)d_in[9];
    const float* lb  = (const float*)d_in[10];

    int N = in_sizes[3];
    int E = in_sizes[2] / 2;
    int B = out_size;
    const int* src = eidx;
    const int* dst = eidx + E;

    char* ws = (char*)d_ws;
    size_t off = 0;
    auto alloc = [&](size_t bytes) -> void* {
        void* p = ws + off;
        off += (bytes + 255) & ~(size_t)255;
        return p;
    };
    unsigned short* bufA = (unsigned short*)alloc((size_t)N * HD * 2);
    unsigned short* bufB = (unsigned short*)alloc((size_t)N * HD * 2);
    int*   rowptr = (int*)  alloc((size_t)(N + 1) * 4);
    int*   cursor = (int*)  alloc((size_t)N * 4);
    int*   colsrc = (int*)  alloc((size_t)E * 4);
    float* pool   = (float*)alloc((size_t)B * HD * 4);
    float* cnt    = (float*)alloc((size_t)B * 4);
    int*   part   = (int*)  alloc(256 * 4);
    int*   partx  = (int*)  alloc(256 * 4);
    unsigned short* wpk = (unsigned short*)alloc((size_t)NL * 2 * 64 * LDW * 2);

    hipMemsetAsync(cursor, 0, (size_t)N * 4, stream);
    hipMemsetAsync(pool, 0, (size_t)B * HD * 4, stream);
    hipMemsetAsync(cnt, 0, (size_t)B * 4, stream);

    int nPart = (N + 255) / 256;

    build_h0_kernel<<<(N * 32 + 255) / 256, 256, 0, stream>>>(x, pos, bufA, N);
    prep_weights_kernel<<<(NL * 2 * 64 * LDW + 255) / 256, 256, 0, stream>>>(W1f, W1r, W2, wpk);
    hist_kernel<<<(E + 255) / 256, 256, 0, stream>>>(dst, E, cursor);
    scan1_kernel<<<nPart, 256, 0, stream>>>(cursor, part, N);
    scan2_kernel<<<1, 256, 0, stream>>>(part, partx, nPart);
    scan3_kernel<<<nPart, 256, 0, stream>>>(cursor, partx, rowptr, N);
    copy_int_kernel<<<(N + 255) / 256, 256, 0, stream>>>(rowptr, cursor, N);
    scatter_kernel<<<(E + 255) / 256, 256, 0, stream>>>(src, dst, E, cursor, colsrc);

    const int gblocks = (N + 63) / 64;
    const int PER_M = 64 * LDW;
    gin_layer_kernel<32, true><<<gblocks, 512, 0, stream>>>(
        bufA, rowptr, colsrc, wpk + 0 * PER_M, wpk + 1 * PER_M, b1, b2, bufB, N);
    unsigned short* cur_in = bufB;
    unsigned short* cur_out = bufA;
    for (int l = 1; l < NL; ++l) {
        const unsigned short* wa = wpk + (size_t)(2 * l + 0) * PER_M;
        const unsigned short* wb = wpk + (size_t)(2 * l + 1) * PER_M;
        const float* ba = b1 + l * HD;
        const float* bb = b2 + l * HD;
        if (l < NL - 1)
            gin_layer_kernel<HD, true><<<gblocks, 512, 0, stream>>>(
                cur_in, rowptr, colsrc, wa, wb, ba, bb, cur_out, N);
        else
            gin_layer_kernel<HD, false><<<gblocks, 512, 0, stream>>>(
                cur_in, rowptr, colsrc, wa, wb, ba, bb, cur_out, N);
        unsigned short* tmp = cur_in; cur_in = cur_out; cur_out = tmp;
    }
    pool_kernel<<<512, 64, 0, stream>>>(cur_in, batch, pool, cnt, N);
    final_kernel<<<B, 64, 0, stream>>>(pool, cnt, lw, lb, (float*)d_out, B);
}

// Round 5
// 341.837 us; speedup vs baseline: 2.7645x; 1.0154x over previous
//
#include <hip/hip_runtime.h>
#include <stdint.h>

#define NF 29
#define HD 64
#define NL 7
#define LDW 72     // padded bf16 row stride (144 B, 16B-aligned)
#define NCHUNK 256 // edge chunks for binned scatter
#define BSH 8      // bucket = dst >> BSH  (256 nodes/bucket, needs N <= 65536)

typedef __attribute__((ext_vector_type(8))) __bf16 bf16x8;
typedef __attribute__((ext_vector_type(4))) float floatx4;

// fp32 -> bf16 bits, round-to-nearest-even
__device__ __forceinline__ unsigned short f2bf(float x) {
    unsigned u = __float_as_uint(x);
    unsigned r = (u + 0x7fffu + ((u >> 16) & 1u)) >> 16;
    return (unsigned short)r;
}
__device__ __forceinline__ unsigned pack_bf2(float x, float y) {
    return (unsigned)f2bf(x) | ((unsigned)f2bf(y) << 16);
}
__device__ __forceinline__ float bflo(uint32_t u) { return __uint_as_float(u << 16); }
__device__ __forceinline__ float bfhi(uint32_t u) { return __uint_as_float(u & 0xffff0000u); }

// ---------------- h0 = concat(x, pos) -> bf16 ----------------
__global__ void build_h0_kernel(const float* __restrict__ x, const float* __restrict__ pos,
                                unsigned short* __restrict__ h0, int N) {
    int t = blockIdx.x * blockDim.x + threadIdx.x;
    if (t >= N * 32) return;
    int n = t >> 5, f = t & 31;
    float v = (f < NF) ? x[n * NF + f] : pos[n * 3 + (f - NF)];
    h0[t] = f2bf(v);
}

// ---------------- weights: fp32 -> transposed, padded bf16 ----------------
__global__ void prep_weights_kernel(const float* __restrict__ W1f, const float* __restrict__ W1r,
                                    const float* __restrict__ W2, unsigned short* __restrict__ wpk) {
    const int PER_M = 64 * LDW;
    int t = blockIdx.x * blockDim.x + threadIdx.x;
    if (t >= NL * 2 * PER_M) return;
    int l = t / (2 * PER_M);
    int r = t - l * 2 * PER_M;
    int m = r / PER_M;
    int q = r - m * PER_M;
    int j = q / LDW, k = q - j * LDW;
    float v = 0.f;
    if (m == 0) {
        int ind = (l == 0) ? 32 : 64;
        if (k < ind) v = (l == 0) ? W1f[k * 64 + j]
                                  : W1r[(size_t)(l - 1) * 4096 + (size_t)k * 64 + j];
    } else {
        if (k < 64) v = W2[(size_t)l * 4096 + (size_t)k * 64 + j];
    }
    wpk[t] = f2bf(v);
}

// ---------------- CSR rowptr: node-degree hist + 3-phase scan ----------------
__global__ void hist_kernel(const int* __restrict__ dst, int E, int* __restrict__ deg) {
    int t = blockIdx.x * blockDim.x + threadIdx.x;
    if (t < E) atomicAdd(&deg[dst[t]], 1);
}

__global__ void scan1_kernel(const int* __restrict__ deg, int* __restrict__ part, int N) {
    int t = threadIdx.x;
    int i = blockIdx.x * 256 + t;
    int v = (i < N) ? deg[i] : 0;
    for (int off = 32; off > 0; off >>= 1) v += __shfl_down(v, off);
    __shared__ int ws[4];
    if ((t & 63) == 0) ws[t >> 6] = v;
    __syncthreads();
    if (t == 0) part[blockIdx.x] = ws[0] + ws[1] + ws[2] + ws[3];
}

__global__ void scan2_kernel(const int* __restrict__ part, int* __restrict__ partx, int nPart) {
    __shared__ int s[256];
    int t = threadIdx.x;
    s[t] = (t < nPart) ? part[t] : 0;
    __syncthreads();
    for (int off = 1; off < 256; off <<= 1) {
        int v = (t >= off) ? s[t - off] : 0;
        __syncthreads();
        s[t] += v;
        __syncthreads();
    }
    partx[t] = (t == 0) ? 0 : s[t - 1];
}

__global__ void scan3_kernel(const int* __restrict__ deg, const int* __restrict__ partx,
                             int* __restrict__ rowptr, int N) {
    int t = threadIdx.x;
    int lane = t & 63, wv = t >> 6;
    int i = blockIdx.x * 256 + t;
    int v = (i < N) ? deg[i] : 0;
    int incl = v;
    for (int off = 1; off < 64; off <<= 1) {
        int u = __shfl_up(incl, off);
        if (lane >= off) incl += u;
    }
    __shared__ int wsum[4];
    if (lane == 63) wsum[wv] = incl;
    __syncthreads();
    int offset = partx[blockIdx.x];
    for (int w = 0; w < wv; ++w) offset += wsum[w];
    int excl = offset + incl - v;
    if (i < N) rowptr[i] = excl;
    if (i == N - 1) rowptr[N] = excl + v;
}

// ---------------- binned scatter pass A1: per-(chunk,bucket) histogram ----------------
__global__ void bucket_hist_kernel(const int* __restrict__ dst, int E, int chunk,
                                   int* __restrict__ bcnt, int nbuk) {
    __shared__ int hist[256];
    int tid = threadIdx.x;
    hist[tid] = 0;
    __syncthreads();
    int lo = blockIdx.x * chunk, hi = min(E, lo + chunk);
    for (int e = lo + tid; e < hi; e += 256) atomicAdd(&hist[dst[e] >> BSH], 1);
    __syncthreads();
    if (tid < nbuk) bcnt[tid * NCHUNK + blockIdx.x] = hist[tid];
}

// ---------------- pass A2: bucket starts + per-(bucket,chunk) offsets ----------------
__global__ void bucket_scan_kernel(const int* __restrict__ bcnt, int* __restrict__ boff,
                                   int* __restrict__ bstart, int nbuk, int E) {
    __shared__ int s[256];
    int t = threadIdx.x;
    int tot = 0;
    if (t < nbuk)
        for (int blk = 0; blk < NCHUNK; ++blk) tot += bcnt[t * NCHUNK + blk];
    s[t] = tot;
    __syncthreads();
    for (int off = 1; off < 256; off <<= 1) {
        int v = (t >= off) ? s[t - off] : 0;
        __syncthreads();
        s[t] += v;
        __syncthreads();
    }
    int start = (t == 0) ? 0 : s[t - 1];
    if (t < nbuk) bstart[t] = start;
    if (t == 0) bstart[nbuk] = E;
    if (t < nbuk) {
        int run = start;
        for (int blk = 0; blk < NCHUNK; ++blk) {
            boff[t * NCHUNK + blk] = run;
            run += bcnt[t * NCHUNK + blk];
        }
    }
}

// ---------------- pass A3: scatter (src,dst) into bucket-grouped ebuf ----------------
__global__ void bucket_scatter_kernel(const int* __restrict__ src, const int* __restrict__ dst,
                                      int E, int chunk, const int* __restrict__ boff,
                                      int2* __restrict__ ebuf, int nbuk) {
    __shared__ int cur[256];
    int tid = threadIdx.x;
    if (tid < nbuk) cur[tid] = boff[tid * NCHUNK + blockIdx.x];
    __syncthreads();
    int lo = blockIdx.x * chunk, hi = min(E, lo + chunk);
    for (int e = lo + tid; e < hi; e += 256) {
        int d = dst[e];
        int p = atomicAdd(&cur[d >> BSH], 1);
        ebuf[p] = make_int2(src[e], d);
    }
}

// ---------------- pass B: within-bucket scatter to final CSR (L2-local window) ----------------
__global__ void final_scatter_kernel(const int2* __restrict__ ebuf, const int* __restrict__ bstart,
                                     const int* __restrict__ rowptr, int* __restrict__ colsrc,
                                     int N) {
    __shared__ int cur[256];
    int b = blockIdx.x, tid = threadIdx.x;
    int node = (b << BSH) + tid;
    cur[tid] = (node < N) ? rowptr[node] : 0;
    __syncthreads();
    int lo = bstart[b], hi = bstart[b + 1];
    for (int e = lo + tid; e < hi; e += 256) {
        int2 ed = ebuf[e];
        int p = atomicAdd(&cur[ed.y & ((1 << BSH) - 1)], 1);
        colsrc[p] = ed.x;
    }
}

// ---------------- fused GIN layer: wide-load gather + MFMA MLP ----------------
template<int IND, bool RELU_OUT>
__global__ __launch_bounds__(512, 8)
void gin_layer_kernel(const unsigned short* __restrict__ hin,
                      const int* __restrict__ rowptr, const int* __restrict__ colsrc,
                      const unsigned short* __restrict__ wAT, const unsigned short* __restrict__ wBT,
                      const float* __restrict__ ba, const float* __restrict__ bb,
                      unsigned short* __restrict__ hout, int N)
{
    __shared__ __align__(16) unsigned short zbuf[64 * LDW];
    __shared__ __align__(16) unsigned short t1buf[64 * LDW];
    __shared__ __align__(16) unsigned short waT[64 * LDW];
    __shared__ __align__(16) unsigned short wbT[64 * LDW];

    const int tid = threadIdx.x;
    const int lane = tid & 63;
    const int w = tid >> 6;
    const int tile0 = blockIdx.x * 64;

    // ---- stage pre-packed bf16 weights: pure uint4 memcpy ----
    {
        const uint4* a4 = (const uint4*)wAT;
        const uint4* b4 = (const uint4*)wBT;
        uint4* da = (uint4*)waT;
        uint4* db = (uint4*)wbT;
        for (int i = tid; i < 64 * LDW / 8; i += 512) { da[i] = a4[i]; db[i] = b4[i]; }
    }

    // ---- gather: group g (8 lanes) owns node tile0 + w*8 + g ----
    const uint4* hin4 = (const uint4*)hin;
    const int g = lane >> 3;
    const int node = tile0 + w * 8 + g;

    int rp;
    {
        int idx = tile0 + w * 8 + (lane < 9 ? lane : 8);
        if (idx > N) idx = N;
        rp = rowptr[idx];
    }
    int e0 = __shfl(rp, g);
    int e1 = __shfl(rp, g + 1);
    if (node >= N) { e0 = 0; e1 = 0; }

    float acc[8] = {0.f, 0.f, 0.f, 0.f, 0.f, 0.f, 0.f, 0.f};
    auto addrow = [&](uint4 u) {
        acc[0] += bflo(u.x); acc[1] += bfhi(u.x);
        acc[2] += bflo(u.y); acc[3] += bfhi(u.y);
        acc[4] += bflo(u.z); acc[5] += bfhi(u.z);
        acc[6] += bflo(u.w); acc[7] += bfhi(u.w);
    };

    if constexpr (IND == 64) {
        const int f4 = lane & 7;                       // 8 chunks x 16B = 128B row
        if (node < N) addrow(hin4[(size_t)node * 8 + f4]);   // self term
        int e = e0;
        for (; e + 7 < e1; e += 8) {                   // 8 loads in flight
            int s[8];
            #pragma unroll
            for (int q = 0; q < 8; ++q) s[q] = colsrc[e + q];
            uint4 u[8];
            #pragma unroll
            for (int q = 0; q < 8; ++q) u[q] = hin4[(size_t)s[q] * 8 + f4];
            #pragma unroll
            for (int q = 0; q < 8; ++q) addrow(u[q]);
        }
        for (; e + 3 < e1; e += 4) {
            int s0 = colsrc[e], s1 = colsrc[e + 1], s2 = colsrc[e + 2], s3 = colsrc[e + 3];
            uint4 u0 = hin4[(size_t)s0 * 8 + f4];
            uint4 u1 = hin4[(size_t)s1 * 8 + f4];
            uint4 u2 = hin4[(size_t)s2 * 8 + f4];
            uint4 u3 = hin4[(size_t)s3 * 8 + f4];
            addrow(u0); addrow(u1); addrow(u2); addrow(u3);
        }
        for (; e < e1; ++e) addrow(hin4[(size_t)colsrc[e] * 8 + f4]);
        uint4 pk;
        pk.x = pack_bf2(acc[0], acc[1]); pk.y = pack_bf2(acc[2], acc[3]);
        pk.z = pack_bf2(acc[4], acc[5]); pk.w = pack_bf2(acc[6], acc[7]);
        *(uint4*)&zbuf[(w * 8 + g) * LDW + f4 * 8] = pk;
    } else {  // IND == 32: 4 chunks/row; group splits into p = 0/1 edge-pair lanes
        const int p = (lane >> 2) & 1;
        const int f4 = lane & 3;
        if (node < N && p == 0) addrow(hin4[(size_t)node * 4 + f4]);  // self once
        int e = e0 + p;
        for (; e + 7 < e1; e += 8) {
            int s0 = colsrc[e], s1 = colsrc[e + 2], s2 = colsrc[e + 4], s3 = colsrc[e + 6];
            uint4 u0 = hin4[(size_t)s0 * 4 + f4];
            uint4 u1 = hin4[(size_t)s1 * 4 + f4];
            uint4 u2 = hin4[(size_t)s2 * 4 + f4];
            uint4 u3 = hin4[(size_t)s3 * 4 + f4];
            addrow(u0); addrow(u1); addrow(u2); addrow(u3);
        }
        while (e < e1) { addrow(hin4[(size_t)colsrc[e] * 4 + f4]); e += 2; }
        #pragma unroll
        for (int i = 0; i < 8; ++i) acc[i] += __shfl_xor(acc[i], 4);
        if (p == 0) {
            uint4 pk;
            pk.x = pack_bf2(acc[0], acc[1]); pk.y = pack_bf2(acc[2], acc[3]);
            pk.z = pack_bf2(acc[4], acc[5]); pk.w = pack_bf2(acc[6], acc[7]);
            *(uint4*)&zbuf[(w * 8 + g) * LDW + f4 * 8] = pk;
        }
    }
    __syncthreads();

    // ---- MFMA MLP ----
    const int n0 = lane & 15, quad = lane >> 4;
    const int stripe = w & 3, jhalf = w >> 2;
    const int row0 = stripe * 16;
    const int jt0 = jhalf * 2, jt1 = jhalf * 2 + 1;

    floatx4 c0, c1;
    {
        float b0v = ba[jt0 * 16 + n0], b1v = ba[jt1 * 16 + n0];
        c0 = (floatx4){b0v, b0v, b0v, b0v};
        c1 = (floatx4){b1v, b1v, b1v, b1v};
    }
    #pragma unroll
    for (int kk = 0; kk < IND / 32; ++kk) {
        bf16x8 a   = *(const bf16x8*)&zbuf[(row0 + n0) * LDW + kk * 32 + quad * 8];
        bf16x8 br0 = *(const bf16x8*)&waT[(jt0 * 16 + n0) * LDW + kk * 32 + quad * 8];
        bf16x8 br1 = *(const bf16x8*)&waT[(jt1 * 16 + n0) * LDW + kk * 32 + quad * 8];
        c0 = __builtin_amdgcn_mfma_f32_16x16x32_bf16(a, br0, c0, 0, 0, 0);
        c1 = __builtin_amdgcn_mfma_f32_16x16x32_bf16(a, br1, c1, 0, 0, 0);
    }
    #pragma unroll
    for (int r = 0; r < 4; ++r) {
        int row = row0 + quad * 4 + r;
        t1buf[row * LDW + jt0 * 16 + n0] = f2bf(fmaxf(c0[r], 0.f));
        t1buf[row * LDW + jt1 * 16 + n0] = f2bf(fmaxf(c1[r], 0.f));
    }
    __syncthreads();

    {
        float b0v = bb[jt0 * 16 + n0], b1v = bb[jt1 * 16 + n0];
        c0 = (floatx4){b0v, b0v, b0v, b0v};
        c1 = (floatx4){b1v, b1v, b1v, b1v};
    }
    #pragma unroll
    for (int kk = 0; kk < 2; ++kk) {
        bf16x8 a   = *(const bf16x8*)&t1buf[(row0 + n0) * LDW + kk * 32 + quad * 8];
        bf16x8 br0 = *(const bf16x8*)&wbT[(jt0 * 16 + n0) * LDW + kk * 32 + quad * 8];
        bf16x8 br1 = *(const bf16x8*)&wbT[(jt1 * 16 + n0) * LDW + kk * 32 + quad * 8];
        c0 = __builtin_amdgcn_mfma_f32_16x16x32_bf16(a, br0, c0, 0, 0, 0);
        c1 = __builtin_amdgcn_mfma_f32_16x16x32_bf16(a, br1, c1, 0, 0, 0);
    }
    #pragma unroll
    for (int r = 0; r < 4; ++r) {
        int row = row0 + quad * 4 + r;
        float v0 = c0[r], v1 = c1[r];
        if (RELU_OUT) { v0 = fmaxf(v0, 0.f); v1 = fmaxf(v1, 0.f); }
        zbuf[row * LDW + jt0 * 16 + n0] = f2bf(v0);
        zbuf[row * LDW + jt1 * 16 + n0] = f2bf(v1);
    }
    __syncthreads();

    // ---- store: 512 threads x uint4 = full 64x128B tile, fully sequential ----
    {
        int nl = tid >> 3, c4 = tid & 7;
        int nodeo = tile0 + nl;
        if (nodeo < N) {
            uint4 v = *(const uint4*)&zbuf[nl * LDW + c4 * 8];
            ((uint4*)hout)[(size_t)nodeo * 8 + c4] = v;
        }
    }
}

// ---------------- global mean pool (partial sums over sorted batch) ----------------
__global__ void pool_kernel(const unsigned short* __restrict__ h, const int* __restrict__ batch,
                            float* __restrict__ pool, float* __restrict__ cnt, int N) {
    int lane = threadIdx.x;  // 64 threads
    int nblk = gridDim.x;
    int per = (N + nblk - 1) / nblk;
    int lo = blockIdx.x * per, hi = min(N, lo + per);
    if (lo >= hi) return;
    int cur = batch[lo];
    float acc = 0.f, c = 0.f;
    for (int n = lo; n < hi; ++n) {
        int b = batch[n];
        if (b != cur) {
            atomicAdd(&pool[cur * HD + lane], acc);
            if (lane == 0) atomicAdd(&cnt[cur], c);
            acc = 0.f; c = 0.f; cur = b;
        }
        acc += __uint_as_float((uint32_t)h[(size_t)n * HD + lane] << 16);
        c += 1.f;
    }
    atomicAdd(&pool[cur * HD + lane], acc);
    if (lane == 0) atomicAdd(&cnt[cur], c);
}

// ---------------- mean + linear head ----------------
__global__ void final_kernel(const float* __restrict__ pool, const float* __restrict__ cnt,
                             const float* __restrict__ lin_w, const float* __restrict__ lin_b,
                             float* __restrict__ out, int B) {
    int b = blockIdx.x;
    int lane = threadIdx.x;
    float c = fmaxf(cnt[b], 1.f);
    float v = pool[b * HD + lane] / c * lin_w[lane];
    for (int off = 32; off > 0; off >>= 1) v += __shfl_down(v, off);
    if (lane == 0) out[b] = v + lin_b[0];
}

extern "C" void kernel_launch(void* const* d_in, const int* in_sizes, int n_in,
                              void* d_out, int out_size, void* d_ws, size_t ws_size,
                              hipStream_t stream)
{
    const float* x   = (const float*)d_in[0];
    const float* pos = (const float*)d_in[1];
    const int*  eidx = (const int*)d_in[2];
    const int* batch = (const int*)d_in[3];
    const float* W1f = (const float*)d_in[4];
    const float* W1r = (const float*)d_in[5];
    const float* b1  = (const float*)d_in[6];
    const float* W2  = (const float*)d_in[7];
    const float* b2  = (const float*)d_in[8];
    const float* lw  = (const float*)d_in[9];
    const float* lb  = (const float*)d_in[10];

    int N = in_sizes[3];
    int E = in_sizes[2] / 2;
    int B = out_size;
    const int* src = eidx;
    const int* dst = eidx + E;

    char* ws = (char*)d_ws;
    size_t off = 0;
    auto alloc = [&](size_t bytes) -> void* {
        void* p = ws + off;
        off += (bytes + 255) & ~(size_t)255;
        return p;
    };
    unsigned short* bufA = (unsigned short*)alloc((size_t)N * HD * 2);
    unsigned short* bufB = (unsigned short*)alloc((size_t)N * HD * 2);
    int*   rowptr = (int*)  alloc((size_t)(N + 1) * 4);
    int*   deg    = (int*)  alloc((size_t)N * 4);
    int*   colsrc = (int*)  alloc((size_t)E * 4);
    int2*  ebuf   = (int2*) alloc((size_t)E * 8);
    float* pool   = (float*)alloc((size_t)B * HD * 4);
    float* cnt    = (float*)alloc((size_t)B * 4);
    int*   part   = (int*)  alloc(256 * 4);
    int*   partx  = (int*)  alloc(256 * 4);
    int*   bcnt   = (int*)  alloc((size_t)256 * NCHUNK * 4);
    int*   boff   = (int*)  alloc((size_t)256 * NCHUNK * 4);
    int*   bstart = (int*)  alloc(257 * 4);
    unsigned short* wpk = (unsigned short*)alloc((size_t)NL * 2 * 64 * LDW * 2);

    hipMemsetAsync(deg, 0, (size_t)N * 4, stream);
    hipMemsetAsync(pool, 0, (size_t)B * HD * 4, stream);
    hipMemsetAsync(cnt, 0, (size_t)B * 4, stream);

    int nPart = (N + 255) / 256;
    int nbuk = (N + (1 << BSH) - 1) >> BSH;   // <= 256 for N <= 65536
    int chunk = (E + NCHUNK - 1) / NCHUNK;

    build_h0_kernel<<<(N * 32 + 255) / 256, 256, 0, stream>>>(x, pos, bufA, N);
    prep_weights_kernel<<<(NL * 2 * 64 * LDW + 255) / 256, 256, 0, stream>>>(W1f, W1r, W2, wpk);
    hist_kernel<<<(E + 255) / 256, 256, 0, stream>>>(dst, E, deg);
    scan1_kernel<<<nPart, 256, 0, stream>>>(deg, part, N);
    scan2_kernel<<<1, 256, 0, stream>>>(part, partx, nPart);
    scan3_kernel<<<nPart, 256, 0, stream>>>(deg, partx, rowptr, N);
    bucket_hist_kernel<<<NCHUNK, 256, 0, stream>>>(dst, E, chunk, bcnt, nbuk);
    bucket_scan_kernel<<<1, 256, 0, stream>>>(bcnt, boff, bstart, nbuk, E);
    bucket_scatter_kernel<<<NCHUNK, 256, 0, stream>>>(src, dst, E, chunk, boff, ebuf, nbuk);
    final_scatter_kernel<<<nbuk, 256, 0, stream>>>(ebuf, bstart, rowptr, colsrc, N);

    const int gblocks = (N + 63) / 64;
    const int PER_M = 64 * LDW;
    gin_layer_kernel<32, true><<<gblocks, 512, 0, stream>>>(
        bufA, rowptr, colsrc, wpk + 0 * PER_M, wpk + 1 * PER_M, b1, b2, bufB, N);
    unsigned short* cur_in = bufB;
    unsigned short* cur_out = bufA;
    for (int l = 1; l < NL; ++l) {
        const unsigned short* wa = wpk + (size_t)(2 * l + 0) * PER_M;
        const unsigned short* wb = wpk + (size_t)(2 * l + 1) * PER_M;
        const float* ba = b1 + l * HD;
        const float* bb = b2 + l * HD;
        if (l < NL - 1)
            gin_layer_kernel<HD, true><<<gblocks, 512, 0, stream>>>(
                cur_in, rowptr, colsrc, wa, wb, ba, bb, cur_out, N);
        else
            gin_layer_kernel<HD, false><<<gblocks, 512, 0, stream>>>(
                cur_in, rowptr, colsrc, wa, wb, ba, bb, cur_out, N);
        unsigned short* tmp = cur_in; cur_in = cur_out; cur_out = tmp;
    }
    pool_kernel<<<512, 64, 0, stream>>>(cur_in, batch, pool, cnt, N);
    final_kernel<<<B, 64, 0, stream>>>(pool, cnt, lw, lb, (float*)d_out, B);
}